// Round 1
// baseline (493.848 us; speedup 1.0000x reference)
//
#include <hip/hip_runtime.h>

#define C_IN 64
#define C_OUT 64
#define HW 224
#define TILE 16
#define NTY (HW / TILE)   // 14
#define CONV_OUT_ELEMS (4 * C_OUT * HW * HW)  // 12,845,056

// ---------------------------------------------------------------------------
// Direct 3x3 conv, NCHW, stride 1, pad 1, fp32 vector path.
// Block: 256 threads = 64 output channels x 4 spatial quadrants (8x8 each).
// Grid:  (14*14 tiles, 4 batches). Loop over the 64 input channels, staging an
// 18x18 halo tile of x and the 64x9 weight slice into LDS each iteration.
// ---------------------------------------------------------------------------
__global__ __launch_bounds__(256) void conv3x3_kernel(
    const float* __restrict__ x, const float* __restrict__ w,
    const float* __restrict__ bias, float* __restrict__ y)
{
    __shared__ float xs[18][20];   // stride 20 floats: keeps 16B alignment per row
    __shared__ float ws[C_OUT * 9];

    const int tid  = threadIdx.x;
    const int co   = tid >> 2;           // 0..63
    const int quad = tid & 3;            // 0..3
    const int qy   = (quad >> 1) * 8;    // 0 or 8
    const int qx   = (quad & 1) * 8;     // 0 or 8
    const int ty   = blockIdx.x / NTY;
    const int tx   = blockIdx.x - ty * NTY;
    const int b    = blockIdx.y;
    const int oy0  = ty * TILE;
    const int ox0  = tx * TILE;

    float acc[8][8];
#pragma unroll
    for (int i = 0; i < 8; ++i)
#pragma unroll
        for (int j = 0; j < 8; ++j) acc[i][j] = 0.f;

    for (int ci = 0; ci < C_IN; ++ci) {
        __syncthreads();  // protect previous iteration's reads
        // ---- stage x halo tile (18x18, zero-padded) ----
        for (int i = tid; i < 18 * 18; i += 256) {
            const int ly = i / 18;
            const int lx = i - ly * 18;
            const int gy = oy0 - 1 + ly;
            const int gx = ox0 - 1 + lx;
            float v = 0.f;
            if ((unsigned)gy < (unsigned)HW && (unsigned)gx < (unsigned)HW)
                v = x[((size_t)(b * C_IN + ci) * HW + gy) * HW + gx];
            xs[ly][lx] = v;
        }
        // ---- stage weight slice: ws[co*9+k] = weight[co][ci][k] ----
        for (int i = tid; i < C_OUT * 9; i += 256) {
            const int c2 = i / 9;
            const int k  = i - c2 * 9;
            ws[i] = w[(size_t)c2 * (C_IN * 9) + ci * 9 + k];
        }
        __syncthreads();

        float wk[9];
#pragma unroll
        for (int k = 0; k < 9; ++k) wk[k] = ws[co * 9 + k];

        // rolling 3-row register window of the thread's 10-wide column slice
        float rows[3][10];
#pragma unroll
        for (int c = 0; c < 10; ++c) rows[0][c] = xs[qy + 0][qx + c];
#pragma unroll
        for (int c = 0; c < 10; ++c) rows[1][c] = xs[qy + 1][qx + c];

#pragma unroll
        for (int i = 0; i < 8; ++i) {
            const int ia = i % 3;
            const int ib = (i + 1) % 3;
            const int ic = (i + 2) % 3;
#pragma unroll
            for (int c = 0; c < 10; ++c) rows[ic][c] = xs[qy + i + 2][qx + c];
#pragma unroll
            for (int j = 0; j < 8; ++j) {
                float s = acc[i][j];
                s += rows[ia][j    ] * wk[0];
                s += rows[ia][j + 1] * wk[1];
                s += rows[ia][j + 2] * wk[2];
                s += rows[ib][j    ] * wk[3];
                s += rows[ib][j + 1] * wk[4];
                s += rows[ib][j + 2] * wk[5];
                s += rows[ic][j    ] * wk[6];
                s += rows[ic][j + 1] * wk[7];
                s += rows[ic][j + 2] * wk[8];
                acc[i][j] = s;
            }
        }
    }

    // ---- epilogue: bias + coalesced float4 stores ----
    const float bv = bias[co];
#pragma unroll
    for (int i = 0; i < 8; ++i) {
        const int gy = oy0 + qy + i;
        float* out = &y[((size_t)(b * C_OUT + co) * HW + gy) * HW + ox0 + qx];
        float4 v0 = make_float4(acc[i][0] + bv, acc[i][1] + bv,
                                acc[i][2] + bv, acc[i][3] + bv);
        float4 v1 = make_float4(acc[i][4] + bv, acc[i][5] + bv,
                                acc[i][6] + bv, acc[i][7] + bv);
        reinterpret_cast<float4*>(out)[0] = v0;
        reinterpret_cast<float4*>(out)[1] = v1;
    }
}

// ---------------------------------------------------------------------------
// Zero-count histogram. For each (b, c, oh, ow): zeros = 9 - #nonzero of
// (3x3 zero-padded patch of x[b,c]) * weight[0,c,:,:]; hist[c][zeros] += 1.
// Block: 256 threads = one 16x16 tile for one (b, c). Wave-level ballot
// aggregation -> LDS counters -> one global float atomic per bin per block.
// ---------------------------------------------------------------------------
__global__ __launch_bounds__(256) void hist_kernel(
    const float* __restrict__ x, const float* __restrict__ w,
    float* __restrict__ hist)
{
    __shared__ float xs[18][20];
    __shared__ int lh[10];

    const int tid = threadIdx.x;
    const int ty  = blockIdx.x / NTY;
    const int tx  = blockIdx.x - ty * NTY;
    const int b   = blockIdx.y;
    const int c   = blockIdx.z;
    const int oy0 = ty * TILE;
    const int ox0 = tx * TILE;

    if (tid < 10) lh[tid] = 0;

    for (int i = tid; i < 18 * 18; i += 256) {
        const int ly = i / 18;
        const int lx = i - ly * 18;
        const int gy = oy0 - 1 + ly;
        const int gx = ox0 - 1 + lx;
        float v = 0.f;
        if ((unsigned)gy < (unsigned)HW && (unsigned)gx < (unsigned)HW)
            v = x[((size_t)(b * C_IN + c) * HW + gy) * HW + gx];
        xs[ly][lx] = v;
    }

    float wk[9];   // weight[0][c][kh][kw] = w[c*9 + k]
#pragma unroll
    for (int k = 0; k < 9; ++k) wk[k] = w[c * 9 + k];
    __syncthreads();

    const int ly = tid >> 4;   // 0..15
    const int lx = tid & 15;   // 0..15
    int cnt = 0;
#pragma unroll
    for (int kh = 0; kh < 3; ++kh)
#pragma unroll
        for (int kw = 0; kw < 3; ++kw) {
            const float p = xs[ly + kh][lx + kw] * wk[kh * 3 + kw];
            cnt += (p != 0.0f) ? 1 : 0;
        }
    const int zeros = 9 - cnt;

#pragma unroll
    for (int k = 0; k < 10; ++k) {
        const unsigned long long m = __ballot(zeros == k);
        if ((tid & 63) == 0 && m != 0ull)
            atomicAdd(&lh[k], (int)__popcll(m));
    }
    __syncthreads();
    if (tid < 10 && lh[tid] > 0)
        atomicAdd(&hist[c * 10 + tid], (float)lh[tid]);
}

extern "C" void kernel_launch(void* const* d_in, const int* in_sizes, int n_in,
                              void* d_out, int out_size, void* d_ws, size_t ws_size,
                              hipStream_t stream) {
    const float* x    = (const float*)d_in[0];   // (4, 64, 224, 224)
    const float* w    = (const float*)d_in[1];   // (64, 64, 3, 3)
    const float* bias = (const float*)d_in[2];   // (64,)
    float* y    = (float*)d_out;                   // (4, 64, 224, 224)
    float* hist = (float*)d_out + CONV_OUT_ELEMS;  // (64, 10)

    // hist area is poisoned 0xAA before every replay — zero it (capture-safe).
    hipMemsetAsync(hist, 0, 64 * 10 * sizeof(float), stream);

    conv3x3_kernel<<<dim3(NTY * NTY, 4), 256, 0, stream>>>(x, w, bias, y);
    hist_kernel<<<dim3(NTY * NTY, 4, C_IN), 256, 0, stream>>>(x, w, hist);
}

// Round 2
// 238.567 us; speedup vs baseline: 2.0701x; 2.0701x over previous
//
#include <hip/hip_runtime.h>

#define HW 224
#define HW2 50176            // 224*224
#define NCH 64
#define CONV_OUT_ELEMS (4 * NCH * HW2)

typedef short bf16x8 __attribute__((ext_vector_type(8)));
typedef float f32x4 __attribute__((ext_vector_type(4)));

// fp32 -> bf16 round-to-nearest-even
__device__ __forceinline__ unsigned short f2bf(float f) {
    unsigned u = __float_as_uint(f);
    u += 0x7FFFu + ((u >> 16) & 1u);
    return (unsigned short)(u >> 16);
}

// ---------------------------------------------------------------------------
// Weight prep: permute w (64co x 64ci x 9tap fp32) into A-fragment order bf16:
// wbuf[chunk2][tap9][mg4][co16][ci32], so an a-frag load is a contiguous 1 KB
// block: lane reads 16B at (lane&15)*64B + (lane>>4)*16B  (A[m=lane&15][k=quad*8+j]).
// ---------------------------------------------------------------------------
__global__ void prep_weights(const float* __restrict__ w,
                             unsigned short* __restrict__ wbuf) {
    const int o = blockIdx.x * 256 + threadIdx.x;
    if (o >= 2 * 9 * 4 * 16 * 32) return;
    const int ci = o & 31;
    const int t1 = o >> 5;
    const int co = t1 & 15;
    const int t2 = t1 >> 4;
    const int mg = t2 & 3;
    const int t3 = t2 >> 2;      // 0..17
    const int tap = t3 % 9;
    const int chunk = t3 / 9;
    wbuf[o] = f2bf(w[((mg * 16 + co) * 64 + (chunk * 32 + ci)) * 9 + tap]);
}

// ---------------------------------------------------------------------------
// Implicit-GEMM conv via mfma_f32_16x16x32_bf16.
// Block (256 thr = 4 waves): 8 rows x 32 cols x all 64 co for one batch b.
// Wave w: rows {2w, 2w+1}; 4 n-groups g: row 2w+(g>>1), cols (g&1)*16..+15.
// K = 64 ci x 9 taps, chunked as 2 x (32 ci); x tile staged in LDS as bf16
// with layout xs[pos = r*34+c][ci32] -> b-frag ds_read_b128 is a contiguous
// 1 KB wave access (conflict-free).
// ---------------------------------------------------------------------------
__global__ __launch_bounds__(256, 2) void conv_mfma(
    const float* __restrict__ x, const unsigned short* __restrict__ wbuf,
    const float* __restrict__ bias, float* __restrict__ y)
{
    __shared__ alignas(16) unsigned short xs[340 * 32];  // 10 rows x 34 cols x 32 ci bf16 = 21.25 KB

    const int tid  = threadIdx.x;
    const int wv   = tid >> 6;
    const int lane = tid & 63;
    const int n    = lane & 15;
    const int q    = lane >> 4;
    const int c0   = blockIdx.x * 32;
    const int r0   = blockIdx.y * 8;
    const int b    = blockIdx.z;

    f32x4 acc[4][4];
#pragma unroll
    for (int mg = 0; mg < 4; ++mg)
#pragma unroll
        for (int g = 0; g < 4; ++g) acc[mg][g] = (f32x4){0.f, 0.f, 0.f, 0.f};

    for (int chunk = 0; chunk < 2; ++chunk) {
        if (chunk) __syncthreads();   // protect previous chunk's reads
        const int ci0 = chunk * 32;

        // ---- stage 10x34 halo tile x 32 ci, bf16, ci-innermost ----
        // 1360 write units; unit i: ci-octet i/340, pos i%340; 8 fp32 loads
        // (coalesced along cols across lanes) -> one ds_write_b128.
        for (int i = tid; i < 1360; i += 256) {
            const int ci8 = i / 340;
            const int pos = i - ci8 * 340;
            const int r   = pos / 34;
            const int c   = pos - r * 34;
            const int gy  = r0 + r - 1;
            const int gx  = c0 + c - 1;
            bf16x8 v;
            if ((unsigned)gy < (unsigned)HW && (unsigned)gx < (unsigned)HW) {
                const float* src =
                    x + ((size_t)(b * NCH + ci0 + ci8 * 8) * HW + gy) * HW + gx;
#pragma unroll
                for (int j = 0; j < 8; ++j) v[j] = (short)f2bf(src[(size_t)j * HW2]);
            } else {
#pragma unroll
                for (int j = 0; j < 8; ++j) v[j] = 0;
            }
            *reinterpret_cast<bf16x8*>(&xs[pos * 32 + ci8 * 8]) = v;
        }
        __syncthreads();

        // ---- K loop: 9 taps x (4 mg x 4 g) MFMAs ----
#pragma unroll
        for (int tap = 0; tap < 9; ++tap) {
            const int dh = tap / 3, dw = tap % 3;
            bf16x8 a[4];
#pragma unroll
            for (int mg = 0; mg < 4; ++mg) {
                const unsigned short* ap =
                    wbuf + ((chunk * 9 + tap) * 4 + mg) * 512 + n * 32 + q * 8;
                a[mg] = *reinterpret_cast<const bf16x8*>(ap);
            }
#pragma unroll
            for (int g = 0; g < 4; ++g) {
                const int rl = 2 * wv + (g >> 1) + dh;
                const int cl = (g & 1) * 16 + dw + n;
                const bf16x8 bf =
                    *reinterpret_cast<const bf16x8*>(&xs[(rl * 34 + cl) * 32 + q * 8]);
#pragma unroll
                for (int mg = 0; mg < 4; ++mg)
                    acc[mg][g] = __builtin_amdgcn_mfma_f32_16x16x32_bf16(
                        a[mg], bf, acc[mg][g], 0, 0, 0);
            }
        }
    }

    // ---- epilogue: C/D layout col=lane&15 (n), row=(lane>>4)*4+reg (co) ----
#pragma unroll
    for (int g = 0; g < 4; ++g) {
        const int row = r0 + 2 * wv + (g >> 1);
        const int col = c0 + (g & 1) * 16 + n;
#pragma unroll
        for (int mg = 0; mg < 4; ++mg) {
#pragma unroll
            for (int rg = 0; rg < 4; ++rg) {
                const int co = mg * 16 + q * 4 + rg;
                y[((size_t)(b * NCH + co) * HW + row) * HW + col] =
                    acc[mg][g][rg] + bias[co];
            }
        }
    }
}

// ---------------------------------------------------------------------------
// Zero-count histogram, one pass over x. Block = one (b, c, 32-row group);
// thread = one row x 28-col segment with a rolling 3x3 window (honest fp32
// product != 0). 10 register bins -> wave shfl reduce -> 1 atomic/bin/wave.
// ---------------------------------------------------------------------------
__global__ __launch_bounds__(256) void hist_kernel(
    const float* __restrict__ x, const float* __restrict__ w,
    float* __restrict__ hist)
{
    const int tid = threadIdx.x;
    const int rg  = blockIdx.x;           // 0..6 (32-row groups)
    const int c   = blockIdx.y;           // input channel
    const int b   = blockIdx.z;
    const int row = rg * 32 + (tid >> 3);
    const int cg  = tid & 7;
    const int cst = cg * 28;

    const float* plane = x + (size_t)(b * NCH + c) * HW2;
    float wk[9];
#pragma unroll
    for (int k = 0; k < 9; ++k) wk[k] = w[c * 9 + k];   // weight[0][c][kh][kw]

    const bool vup = row > 0, vdn = row < HW - 1;
    const float* pu = plane + (size_t)(row - 1) * HW;
    const float* pm = plane + (size_t)row * HW;
    const float* pd = plane + (size_t)(row + 1) * HW;

    float u0, u1, m0, m1, d0, d1;
    if (cst == 0) { u0 = 0.f; m0 = 0.f; d0 = 0.f; }
    else {
        u0 = vup ? pu[cst - 1] : 0.f;
        m0 = pm[cst - 1];
        d0 = vdn ? pd[cst - 1] : 0.f;
    }
    u1 = vup ? pu[cst] : 0.f;
    m1 = pm[cst];
    d1 = vdn ? pd[cst] : 0.f;

    int h[10];
#pragma unroll
    for (int k = 0; k < 10; ++k) h[k] = 0;

    for (int cc = cst; cc < cst + 28; ++cc) {
        const int nc = cc + 1;
        const bool vr = nc < HW;
        const float u2 = (vup && vr) ? pu[nc] : 0.f;
        const float m2 = vr ? pm[nc] : 0.f;
        const float d2 = (vdn && vr) ? pd[nc] : 0.f;
        int cnt = 0;
        cnt += (u0 * wk[0] != 0.f); cnt += (u1 * wk[1] != 0.f); cnt += (u2 * wk[2] != 0.f);
        cnt += (m0 * wk[3] != 0.f); cnt += (m1 * wk[4] != 0.f); cnt += (m2 * wk[5] != 0.f);
        cnt += (d0 * wk[6] != 0.f); cnt += (d1 * wk[7] != 0.f); cnt += (d2 * wk[8] != 0.f);
        const int z = 9 - cnt;
#pragma unroll
        for (int k = 0; k < 10; ++k) h[k] += (z == k);
        u0 = u1; u1 = u2; m0 = m1; m1 = m2; d0 = d1; d1 = d2;
    }

#pragma unroll
    for (int k = 0; k < 10; ++k) {
        int v = h[k];
        v += __shfl_xor(v, 32);
        v += __shfl_xor(v, 16);
        v += __shfl_xor(v, 8);
        v += __shfl_xor(v, 4);
        v += __shfl_xor(v, 2);
        v += __shfl_xor(v, 1);
        if ((tid & 63) == 0 && v != 0)
            atomicAdd(&hist[c * 10 + k], (float)v);
    }
}

extern "C" void kernel_launch(void* const* d_in, const int* in_sizes, int n_in,
                              void* d_out, int out_size, void* d_ws, size_t ws_size,
                              hipStream_t stream) {
    const float* x    = (const float*)d_in[0];   // (4, 64, 224, 224)
    const float* w    = (const float*)d_in[1];   // (64, 64, 3, 3)
    const float* bias = (const float*)d_in[2];   // (64,)
    float* y    = (float*)d_out;
    float* hist = (float*)d_out + CONV_OUT_ELEMS;
    unsigned short* wbuf = (unsigned short*)d_ws;  // 73728 B

    hipMemsetAsync(hist, 0, 64 * 10 * sizeof(float), stream);
    prep_weights<<<144, 256, 0, stream>>>(w, wbuf);
    conv_mfma<<<dim3(7, 28, 4), 256, 0, stream>>>(x, wbuf, bias, y);
    hist_kernel<<<dim3(7, 64, 4), 256, 0, stream>>>(x, w, hist);
}

// Round 4
// 169.825 us; speedup vs baseline: 2.9080x; 1.4048x over previous
//
#include <hip/hip_runtime.h>

#define HW 224
#define HW2 50176            // 224*224
#define NCH 64
#define NPIX (4 * HW2)       // 200704 pixels total
#define CONV_OUT_ELEMS (4 * NCH * HW2)

typedef short bf16x8 __attribute__((ext_vector_type(8)));
typedef float f32x4 __attribute__((ext_vector_type(4)));

// fp32 -> bf16 round-to-nearest-even
__device__ __forceinline__ unsigned short f2bf(float f) {
    unsigned u = __float_as_uint(f);
    u += 0x7FFFu + ((u >> 16) & 1u);
    return (unsigned short)(u >> 16);
}

// ===========================================================================
// MAIN PATH (needs ws >= 73728 + 25690112 bytes)
// ===========================================================================

// Weight prep v2: A-frag lane-major bf16. wbufA elem offset:
//   o = (k*4 + mg)*512 + lane*8 + j,  lane = n + 16q
//   value = w[co = mg*16+n][ci = (k&1)*32 + q*8 + j][tap = k>>1]
// so conv's a-frag load is base + lane*16B — one contiguous 1 KB wave load.
__global__ __launch_bounds__(256) void prep_weights_v2(
    const float* __restrict__ w, unsigned short* __restrict__ wbufA) {
    const int o = blockIdx.x * 256 + threadIdx.x;
    if (o >= 18 * 2048) return;            // 36864 elems
    const int j    = o & 7;
    const int lane = (o >> 3) & 63;
    const int n    = lane & 15;
    const int q    = lane >> 4;
    const int mg   = (o >> 9) & 3;
    const int k    = o >> 11;              // 0..17
    const int tap  = k >> 1;
    const int half = k & 1;
    const int ci   = half * 32 + q * 8 + j;
    const int co   = mg * 16 + n;
    wbufA[o] = f2bf(w[(co * 64 + ci) * 9 + tap]);
}

// x prep: NCHW fp32 -> NHWC bf16 (xbf[b][y][x][ci]).
// Thread = (pixel, ci-octet). 200704 pixels / 32 per block = 6272 blocks.
__global__ __launch_bounds__(256) void prep_x(
    const float* __restrict__ xf, unsigned short* __restrict__ xbf) {
    const int tid = threadIdx.x;
    const int pix = blockIdx.x * 32 + (tid >> 3);
    if (pix >= NPIX) return;               // guard (grid is exact, but be safe)
    const int oct = tid & 7;
    const int b   = pix / HW2;
    const int rem = pix - b * HW2;
    const float* src = xf + (size_t)(b * NCH + oct * 8) * HW2 + rem;
    bf16x8 v;
#pragma unroll
    for (int j = 0; j < 8; ++j) v[j] = (short)f2bf(src[(size_t)j * HW2]);
    *reinterpret_cast<bf16x8*>(xbf + (size_t)pix * 64 + oct * 8) = v;
}

// Conv v2: implicit GEMM on NHWC bf16 input.
// Block (4 waves): 8 rows x 32 cols x all 64 co, one batch. Whole K (64ci x
// 9tap) from one LDS tile: xs[pos = r*34+c][ci64], stored as 16B blocks with
// XOR swizzle  phys16 = pos*8 + (blk ^ (pos&7))  -> both staging ds_writes
// and b-frag ds_reads hit each bank exactly 8x per wave access (minimum).
__global__ __launch_bounds__(256, 3) void conv_mfma_v2(
    const unsigned short* __restrict__ xbf,
    const unsigned short* __restrict__ wbufA,
    const float* __restrict__ bias, float* __restrict__ y)
{
    __shared__ alignas(16) unsigned short xs[340 * 64];  // 43520 B

    const int tid  = threadIdx.x;
    const int wv   = tid >> 6;
    const int lane = tid & 63;
    const int n    = lane & 15;
    const int q    = lane >> 4;
    const int c0   = blockIdx.x * 32;
    const int r0   = blockIdx.y * 8;
    const int b    = blockIdx.z;

    // ---- stage full halo tile: 340 pos x 8 blk 16B units, pure copies ----
    for (int i = tid; i < 2720; i += 256) {
        const int pos = i >> 3;
        const int blk = i & 7;
        const int rr  = pos / 34;
        const int cc  = pos - rr * 34;
        const int gy  = r0 + rr - 1;
        const int gx  = c0 + cc - 1;
        const int phys = pos * 8 + (blk ^ (pos & 7));
        bf16x8 v = (bf16x8){0, 0, 0, 0, 0, 0, 0, 0};
        if ((unsigned)gy < (unsigned)HW && (unsigned)gx < (unsigned)HW)
            v = *reinterpret_cast<const bf16x8*>(
                xbf + ((size_t)(b * HW + gy) * HW + gx) * 64 + blk * 8);
        *reinterpret_cast<bf16x8*>(xs + phys * 8) = v;
    }
    __syncthreads();

    f32x4 acc[4][4];
#pragma unroll
    for (int mg = 0; mg < 4; ++mg)
#pragma unroll
        for (int g = 0; g < 4; ++g) acc[mg][g] = (f32x4){0.f, 0.f, 0.f, 0.f};

    // ---- K loop: 9 taps x 2 ci-halves, 16 MFMAs each ----
#pragma unroll
    for (int tap = 0; tap < 9; ++tap) {
        const int dh = tap / 3, dw = tap % 3;
#pragma unroll
        for (int half = 0; half < 2; ++half) {
            const int k = tap * 2 + half;
            bf16x8 a[4];
#pragma unroll
            for (int mg = 0; mg < 4; ++mg)
                a[mg] = *reinterpret_cast<const bf16x8*>(
                    wbufA + (k * 4 + mg) * 512 + lane * 8);
#pragma unroll
            for (int g = 0; g < 4; ++g) {
                const int pos = (2 * wv + (g >> 1) + dh) * 34
                              + (g & 1) * 16 + dw + n;
                const int phys = pos * 8 + ((half * 4 + q) ^ (pos & 7));
                const bf16x8 bf =
                    *reinterpret_cast<const bf16x8*>(xs + phys * 8);
#pragma unroll
                for (int mg = 0; mg < 4; ++mg)
                    acc[mg][g] = __builtin_amdgcn_mfma_f32_16x16x32_bf16(
                        a[mg], bf, acc[mg][g], 0, 0, 0);
            }
        }
    }

    // ---- epilogue: C/D col=lane&15 (spatial), row=q*4+reg (co) ----
#pragma unroll
    for (int g = 0; g < 4; ++g) {
        const int row = r0 + 2 * wv + (g >> 1);
        const int col = c0 + (g & 1) * 16 + n;
#pragma unroll
        for (int mg = 0; mg < 4; ++mg) {
#pragma unroll
            for (int rg = 0; rg < 4; ++rg) {
                const int co = mg * 16 + q * 4 + rg;
                y[((size_t)(b * NCH + co) * HW + row) * HW + col] =
                    acc[mg][g][rg] + bias[co];
            }
        }
    }
}

// ===========================================================================
// Hist v2: lane = column (coalesced), rolling 3-row register window.
// Block = (rowgroup of 28, c, b). Per-thread 10 bins -> shfl reduce ->
// LDS -> 10 global atomics per block.
// ===========================================================================
__global__ __launch_bounds__(256) void hist_v2(
    const float* __restrict__ x, const float* __restrict__ w,
    float* __restrict__ hist)
{
    __shared__ int lh[10];
    const int tid = threadIdx.x;
    const int col = tid;                 // active iff < 224
    const int rg  = blockIdx.x;          // 0..7
    const int c   = blockIdx.y;
    const int b   = blockIdx.z;
    if (tid < 10) lh[tid] = 0;
    __syncthreads();

    int h[10];
#pragma unroll
    for (int k = 0; k < 10; ++k) h[k] = 0;

    if (col < HW) {
        const float* plane = x + (size_t)(b * NCH + c) * HW2;
        float wk[9];
#pragma unroll
        for (int k = 0; k < 9; ++k) wk[k] = w[c * 9 + k];

        const bool vl = col > 0, vr = col < HW - 1;
        const int r0 = rg * 28;
        float u0, u1, u2, m0, m1, m2;
        if (r0 > 0) {
            const float* p = plane + (size_t)(r0 - 1) * HW + col;
            u0 = vl ? p[-1] : 0.f; u1 = p[0]; u2 = vr ? p[1] : 0.f;
        } else { u0 = u1 = u2 = 0.f; }
        {
            const float* p = plane + (size_t)r0 * HW + col;
            m0 = vl ? p[-1] : 0.f; m1 = p[0]; m2 = vr ? p[1] : 0.f;
        }

        for (int r = r0; r < r0 + 28; ++r) {
            float d0, d1, d2;
            if (r + 1 < HW) {
                const float* p = plane + (size_t)(r + 1) * HW + col;
                d0 = vl ? p[-1] : 0.f; d1 = p[0]; d2 = vr ? p[1] : 0.f;
            } else { d0 = d1 = d2 = 0.f; }

            int cnt = 0;
            cnt += (u0 * wk[0] != 0.f); cnt += (u1 * wk[1] != 0.f); cnt += (u2 * wk[2] != 0.f);
            cnt += (m0 * wk[3] != 0.f); cnt += (m1 * wk[4] != 0.f); cnt += (m2 * wk[5] != 0.f);
            cnt += (d0 * wk[6] != 0.f); cnt += (d1 * wk[7] != 0.f); cnt += (d2 * wk[8] != 0.f);
            const int z = 9 - cnt;
#pragma unroll
            for (int k = 0; k < 10; ++k) h[k] += (z == k);
            u0 = m0; u1 = m1; u2 = m2; m0 = d0; m1 = d1; m2 = d2;
        }
    }

#pragma unroll
    for (int k = 0; k < 10; ++k) {
        int v = h[k];
        v += __shfl_xor(v, 32); v += __shfl_xor(v, 16); v += __shfl_xor(v, 8);
        v += __shfl_xor(v, 4);  v += __shfl_xor(v, 2);  v += __shfl_xor(v, 1);
        if ((tid & 63) == 0 && v != 0) atomicAdd(&lh[k], v);
    }
    __syncthreads();
    if (tid < 10 && lh[tid] > 0)
        atomicAdd(&hist[c * 10 + tid], (float)lh[tid]);
}

// ===========================================================================
// FALLBACK PATH (round-2 kernels, ws >= 73728 B only)
// ===========================================================================
__global__ void prep_weights_fb(const float* __restrict__ w,
                                unsigned short* __restrict__ wbuf) {
    const int o = blockIdx.x * 256 + threadIdx.x;
    if (o >= 2 * 9 * 4 * 16 * 32) return;
    const int ci = o & 31;
    const int t1 = o >> 5;
    const int co = t1 & 15;
    const int t2 = t1 >> 4;
    const int mg = t2 & 3;
    const int t3 = t2 >> 2;
    const int tap = t3 % 9;
    const int chunk = t3 / 9;
    wbuf[o] = f2bf(w[((mg * 16 + co) * 64 + (chunk * 32 + ci)) * 9 + tap]);
}

__global__ __launch_bounds__(256, 2) void conv_mfma_fb(
    const float* __restrict__ x, const unsigned short* __restrict__ wbuf,
    const float* __restrict__ bias, float* __restrict__ y)
{
    __shared__ alignas(16) unsigned short xs[340 * 32];
    const int tid  = threadIdx.x;
    const int wv   = tid >> 6;
    const int lane = tid & 63;
    const int n    = lane & 15;
    const int q    = lane >> 4;
    const int c0   = blockIdx.x * 32;
    const int r0   = blockIdx.y * 8;
    const int b    = blockIdx.z;

    f32x4 acc[4][4];
#pragma unroll
    for (int mg = 0; mg < 4; ++mg)
#pragma unroll
        for (int g = 0; g < 4; ++g) acc[mg][g] = (f32x4){0.f, 0.f, 0.f, 0.f};

    for (int chunk = 0; chunk < 2; ++chunk) {
        if (chunk) __syncthreads();
        const int ci0 = chunk * 32;
        for (int i = tid; i < 1360; i += 256) {
            const int ci8 = i / 340;
            const int pos = i - ci8 * 340;
            const int r   = pos / 34;
            const int c   = pos - r * 34;
            const int gy  = r0 + r - 1;
            const int gx  = c0 + c - 1;
            bf16x8 v;
            if ((unsigned)gy < (unsigned)HW && (unsigned)gx < (unsigned)HW) {
                const float* src =
                    x + ((size_t)(b * NCH + ci0 + ci8 * 8) * HW + gy) * HW + gx;
#pragma unroll
                for (int j = 0; j < 8; ++j) v[j] = (short)f2bf(src[(size_t)j * HW2]);
            } else {
#pragma unroll
                for (int j = 0; j < 8; ++j) v[j] = 0;
            }
            *reinterpret_cast<bf16x8*>(&xs[pos * 32 + ci8 * 8]) = v;
        }
        __syncthreads();

#pragma unroll
        for (int tap = 0; tap < 9; ++tap) {
            const int dh = tap / 3, dw = tap % 3;
            bf16x8 a[4];
#pragma unroll
            for (int mg = 0; mg < 4; ++mg) {
                const unsigned short* ap =
                    wbuf + ((chunk * 9 + tap) * 4 + mg) * 512 + n * 32 + q * 8;
                a[mg] = *reinterpret_cast<const bf16x8*>(ap);
            }
#pragma unroll
            for (int g = 0; g < 4; ++g) {
                const int rl = 2 * wv + (g >> 1) + dh;
                const int cl = (g & 1) * 16 + dw + n;
                const bf16x8 bf =
                    *reinterpret_cast<const bf16x8*>(&xs[(rl * 34 + cl) * 32 + q * 8]);
#pragma unroll
                for (int mg = 0; mg < 4; ++mg)
                    acc[mg][g] = __builtin_amdgcn_mfma_f32_16x16x32_bf16(
                        a[mg], bf, acc[mg][g], 0, 0, 0);
            }
        }
    }

#pragma unroll
    for (int g = 0; g < 4; ++g) {
        const int row = r0 + 2 * wv + (g >> 1);
        const int col = c0 + (g & 1) * 16 + n;
#pragma unroll
        for (int mg = 0; mg < 4; ++mg) {
#pragma unroll
            for (int rg = 0; rg < 4; ++rg) {
                const int co = mg * 16 + q * 4 + rg;
                y[((size_t)(b * NCH + co) * HW + row) * HW + col] =
                    acc[mg][g][rg] + bias[co];
            }
        }
    }
}

// ===========================================================================
extern "C" void kernel_launch(void* const* d_in, const int* in_sizes, int n_in,
                              void* d_out, int out_size, void* d_ws, size_t ws_size,
                              hipStream_t stream) {
    const float* x    = (const float*)d_in[0];
    const float* w    = (const float*)d_in[1];
    const float* bias = (const float*)d_in[2];
    float* y    = (float*)d_out;
    float* hist = (float*)d_out + CONV_OUT_ELEMS;

    hipMemsetAsync(hist, 0, 64 * 10 * sizeof(float), stream);

    const size_t NEED = 73728 + (size_t)NPIX * 64 * 2;  // 25,763,840 B
    if (ws_size >= NEED) {
        unsigned short* wbufA = (unsigned short*)d_ws;          // 73728 B
        unsigned short* xbf   = (unsigned short*)d_ws + 36864;  // NHWC bf16
        prep_weights_v2<<<144, 256, 0, stream>>>(w, wbufA);
        prep_x<<<NPIX / 32, 256, 0, stream>>>(x, xbf);          // 6272 blocks
        conv_mfma_v2<<<dim3(7, 28, 4), 256, 0, stream>>>(xbf, wbufA, bias, y);
    } else {
        unsigned short* wbuf = (unsigned short*)d_ws;
        prep_weights_fb<<<144, 256, 0, stream>>>(w, wbuf);
        conv_mfma_fb<<<dim3(7, 28, 4), 256, 0, stream>>>(x, wbuf, bias, y);
    }
    hist_v2<<<dim3(8, 64, 4), 256, 0, stream>>>(x, w, hist);
}